// Round 1
// baseline (596.657 us; speedup 1.0000x reference)
//
#include <hip/hip_runtime.h>

// Problem: B=8, Tq=2048, Tk=2048, D=1024 (all fp32 in/out)
//   scores  = Q @ K^T            [B,Tq,Tk]
//   weights = softmax(scores)    (output 1, at d_out + 16777216)
//   context = weights @ K        (output 0, at d_out)
//
// ws layout (needs 96 MB):
//   Qh  f16 [B][Tq][D]   @ 0        (32 MB)
//   Kh  f16 [B][Tk][D]   @ 32 MB
//   Kt  f16 [B][D][Tk]   @ 64 MB

typedef _Float16 f16;
typedef _Float16 half4 __attribute__((ext_vector_type(4)));
typedef _Float16 half8 __attribute__((ext_vector_type(8)));
typedef float floatx4 __attribute__((ext_vector_type(4)));

#define BM 128
#define BN 128
#define BK 32

__device__ __forceinline__ void gl2lds16(const void* g, void* l) {
    __builtin_amdgcn_global_load_lds(
        (const __attribute__((address_space(1))) unsigned int*)g,
        (__attribute__((address_space(3))) unsigned int*)l,
        16, 0, 0);
}

// ---- fp32 -> fp16 convert (Q) ----
__global__ __launch_bounds__(256) void q_cvt(const float* __restrict__ src,
                                             f16* __restrict__ dst, int n4) {
    int i = blockIdx.x * 256 + threadIdx.x;
    if (i >= n4) return;
    float4 v = ((const float4*)src)[i];
    half4 h;
    h[0] = (f16)v.x; h[1] = (f16)v.y; h[2] = (f16)v.z; h[3] = (f16)v.w;
    ((half4*)dst)[i] = h;
}

// ---- K: fp32 -> fp16 row-major copy + transposed copy ----
__global__ __launch_bounds__(256) void k_cvt_transpose(const float* __restrict__ K,
                                                       f16* __restrict__ Kh,
                                                       f16* __restrict__ Kt) {
    __shared__ f16 tile[32][33];
    const int b  = blockIdx.z;
    const int k0 = blockIdx.y * 32;   // Tk tile
    const int d0 = blockIdx.x * 32;   // D tile
    const int tx = threadIdx.x;       // 0..31
    const int ty = threadIdx.y;       // 0..7
    const float* src = K + (size_t)b * 2048 * 1024;
    f16* khb = Kh + (size_t)b * 2048 * 1024;
    f16* ktb = Kt + (size_t)b * 1024 * 2048;
    #pragma unroll
    for (int i = ty; i < 32; i += 8) {
        f16 v = (f16)src[(size_t)(k0 + i) * 1024 + d0 + tx];
        tile[i][tx] = v;
        khb[(size_t)(k0 + i) * 1024 + d0 + tx] = v;   // coalesced in d
    }
    __syncthreads();
    #pragma unroll
    for (int i = ty; i < 32; i += 8) {
        ktb[(size_t)(d0 + i) * 2048 + k0 + tx] = tile[tx][i];  // coalesced in k
    }
}

// ---- m97-style bt-GEMM: C[M,N] = A[M,K_] * B[N,K_]^T, fp16 MFMA, fp32 out ----
// AF32: A source is fp32 (converted to f16 during staging); else f16 via global_load_lds.
template <bool AF32>
__global__ __launch_bounds__(256) void gemm_bt(const void* __restrict__ Av,
                                               const f16* __restrict__ Bmat,
                                               float* __restrict__ C,
                                               int K_, int N,
                                               long sA, long sB, long sC) {
    __shared__ f16 As[BM * BK];   // 8 KB
    __shared__ f16 Bs[BN * BK];   // 8 KB
    const int tid  = threadIdx.x;
    const int lane = tid & 63;
    const int wave = tid >> 6;
    const int wm = (wave & 1) * 64;
    const int wn = (wave >> 1) * 64;
    const int tileM = blockIdx.y * BM;
    const int tileN = blockIdx.x * BN;
    const int bz = blockIdx.z;
    const f16* Bb = Bmat + (size_t)bz * sB;
    float* Cb = C + (size_t)bz * sC;

    floatx4 zero = {0.f, 0.f, 0.f, 0.f};
    floatx4 acc[4][4];
    #pragma unroll
    for (int i = 0; i < 4; i++)
        #pragma unroll
        for (int j = 0; j < 4; j++) acc[i][j] = zero;

    for (int k0 = 0; k0 < K_; k0 += BK) {
        if constexpr (AF32) {
            const float* Ab = (const float*)Av + (size_t)bz * sA;
            #pragma unroll
            for (int r = 0; r < 2; r++) {
                int h = (r * 256 + tid) * 8;
                int row = h >> 5, col = h & 31;
                const float* s = Ab + (size_t)(tileM + row) * K_ + k0 + col;
                float4 v0 = *(const float4*)s;
                float4 v1 = *(const float4*)(s + 4);
                half8 hv;
                hv[0] = (f16)v0.x; hv[1] = (f16)v0.y; hv[2] = (f16)v0.z; hv[3] = (f16)v0.w;
                hv[4] = (f16)v1.x; hv[5] = (f16)v1.y; hv[6] = (f16)v1.z; hv[7] = (f16)v1.w;
                *(half8*)&As[h] = hv;
            }
        } else {
            const f16* Ab = (const f16*)Av + (size_t)bz * sA;
            #pragma unroll
            for (int r = 0; r < 2; r++) {
                int h = (r * 256 + tid) * 8;
                int row = h >> 5, col = h & 31;
                gl2lds16(Ab + (size_t)(tileM + row) * K_ + k0 + col, &As[h]);
            }
        }
        #pragma unroll
        for (int r = 0; r < 2; r++) {
            int h = (r * 256 + tid) * 8;
            int row = h >> 5, col = h & 31;
            gl2lds16(Bb + (size_t)(tileN + row) * K_ + k0 + col, &Bs[h]);
        }
        __syncthreads();

        const int mr = lane & 15;
        const int kq = (lane >> 4) * 8;
        half8 af[4], bf[4];
        #pragma unroll
        for (int i = 0; i < 4; i++)
            af[i] = *(const half8*)&As[(wm + i * 16 + mr) * BK + kq];
        #pragma unroll
        for (int j = 0; j < 4; j++)
            bf[j] = *(const half8*)&Bs[(wn + j * 16 + mr) * BK + kq];
        #pragma unroll
        for (int i = 0; i < 4; i++)
            #pragma unroll
            for (int j = 0; j < 4; j++)
                acc[i][j] = __builtin_amdgcn_mfma_f32_16x16x32_f16(af[i], bf[j], acc[i][j], 0, 0, 0);
        __syncthreads();
    }

    // epilogue: C/D layout col=lane&15, row=(lane>>4)*4+reg
    const int r0 = (lane >> 4) * 4;
    const int cn = lane & 15;
    #pragma unroll
    for (int i = 0; i < 4; i++) {
        #pragma unroll
        for (int j = 0; j < 4; j++) {
            int col = tileN + wn + j * 16 + cn;
            #pragma unroll
            for (int r = 0; r < 4; r++) {
                int row = tileM + wm + i * 16 + r0 + r;
                Cb[(size_t)row * N + col] = acc[i][j][r];
            }
        }
    }
}

// ---- in-place row softmax, one block (256 thr) per row of 2048 ----
__global__ __launch_bounds__(256) void softmax_rows(float* __restrict__ S) {
    const size_t row = blockIdx.x;
    float* p = S + row * 2048;
    const int tid = threadIdx.x;
    const int lane = tid & 63;
    const int wave = tid >> 6;
    __shared__ float red[8];

    float4 va = ((const float4*)p)[tid];
    float4 vb = ((const float4*)p)[tid + 256];
    float m = fmaxf(fmaxf(fmaxf(va.x, va.y), fmaxf(va.z, va.w)),
                    fmaxf(fmaxf(vb.x, vb.y), fmaxf(vb.z, vb.w)));
    #pragma unroll
    for (int off = 32; off; off >>= 1) m = fmaxf(m, __shfl_xor(m, off));
    if (lane == 0) red[wave] = m;
    __syncthreads();
    m = fmaxf(fmaxf(red[0], red[1]), fmaxf(red[2], red[3]));

    va.x = __expf(va.x - m); va.y = __expf(va.y - m);
    va.z = __expf(va.z - m); va.w = __expf(va.w - m);
    vb.x = __expf(vb.x - m); vb.y = __expf(vb.y - m);
    vb.z = __expf(vb.z - m); vb.w = __expf(vb.w - m);
    float s = va.x + va.y + va.z + va.w + vb.x + vb.y + vb.z + vb.w;
    #pragma unroll
    for (int off = 32; off; off >>= 1) s += __shfl_xor(s, off);
    if (lane == 0) red[4 + wave] = s;
    __syncthreads();
    s = red[4] + red[5] + red[6] + red[7];
    float inv = 1.0f / s;
    va.x *= inv; va.y *= inv; va.z *= inv; va.w *= inv;
    vb.x *= inv; vb.y *= inv; vb.z *= inv; vb.w *= inv;
    ((float4*)p)[tid] = va;
    ((float4*)p)[tid + 256] = vb;
}

extern "C" void kernel_launch(void* const* d_in, const int* in_sizes, int n_in,
                              void* d_out, int out_size, void* d_ws, size_t ws_size,
                              hipStream_t stream) {
    const float* Q = (const float*)d_in[0];   // [8,2048,1024]
    const float* K = (const float*)d_in[1];   // [8,2048,1024]
    float* ctx = (float*)d_out;               // [8,2048,1024]
    float* W   = (float*)d_out + 16777216;    // [8,2048,2048]

    f16* Qh = (f16*)d_ws;        // 32 MB
    f16* Kh = Qh + 16777216;     // 32 MB
    f16* Kt = Kh + 16777216;     // 32 MB, [B][D][Tk]

    // 1. converts
    q_cvt<<<16384, 256, 0, stream>>>(Q, Qh, 4194304);
    k_cvt_transpose<<<dim3(32, 64, 8), dim3(32, 8), 0, stream>>>(K, Kh, Kt);

    // 2. scores = Q @ K^T  (M=2048, N=2048, K_=1024) -> W region (raw scores)
    gemm_bt<false><<<dim3(16, 16, 8), 256, 0, stream>>>(
        Qh, Kh, W, 1024, 2048, 2048L * 1024, 2048L * 1024, 2048L * 2048);

    // 3. softmax rows (16384 rows of 2048), in place
    softmax_rows<<<16384, 256, 0, stream>>>(W);

    // 4. context = W @ K = W[M,K_] * Kt[N,K_]^T  (M=2048, N=1024, K_=2048)
    gemm_bt<true><<<dim3(8, 16, 8), 256, 0, stream>>>(
        W, Kt, ctx, 2048, 1024, 2048L * 2048, 1024L * 2048, 2048L * 1024);
}

// Round 2
// 564.066 us; speedup vs baseline: 1.0578x; 1.0578x over previous
//
#include <hip/hip_runtime.h>

// Problem: B=8, Tq=2048, Tk=2048, D=1024 (all fp32 in/out)
//   scores  = Q @ K^T            [B,Tq,Tk]
//   weights = softmax(scores)    (output 1, at d_out + 16777216)
//   context = weights @ K        (output 0, at d_out)
//
// ws layout (96 MB):
//   phase 1:  Qh f16 [B][Tq][D] @ 0       (32 MB)
//             Kh f16 [B][Tk][D] @ 32 MB   (32 MB)
//             Kt f16 [B][D][Tk] @ 64 MB   (32 MB)
//   phase 2 (after QK GEMM, Qh/Kh dead):
//             Wh f16 [B][Tq][Tk] @ 0      (64 MB)   <- written by softmax
//
// XCD trick: grid dim3(8, tiles) -> flat block id % 8 == blockIdx.x == batch,
// so each batch's blocks land on one XCD; consecutive y (N-tile fastest)
// share the A-row tile in that XCD's L2.

typedef _Float16 f16;
typedef _Float16 half4 __attribute__((ext_vector_type(4)));
typedef _Float16 half8 __attribute__((ext_vector_type(8)));
typedef float floatx4 __attribute__((ext_vector_type(4)));

#define BM 128
#define BN 128
#define BK 32

__device__ __forceinline__ void gl2lds16(const void* g, void* l) {
    __builtin_amdgcn_global_load_lds(
        (const __attribute__((address_space(1))) unsigned int*)g,
        (__attribute__((address_space(3))) unsigned int*)l,
        16, 0, 0);
}

// ---- fp32 -> fp16 convert ----
__global__ __launch_bounds__(256) void cvt_f32_f16(const float* __restrict__ src,
                                                   f16* __restrict__ dst, int n4) {
    int i = blockIdx.x * 256 + threadIdx.x;
    if (i >= n4) return;
    float4 v = ((const float4*)src)[i];
    half4 h;
    h[0] = (f16)v.x; h[1] = (f16)v.y; h[2] = (f16)v.z; h[3] = (f16)v.w;
    ((half4*)dst)[i] = h;
}

// ---- K: fp32 -> fp16 row-major copy + transposed copy ----
__global__ __launch_bounds__(256) void k_cvt_transpose(const float* __restrict__ K,
                                                       f16* __restrict__ Kh,
                                                       f16* __restrict__ Kt) {
    __shared__ f16 tile[32][33];
    const int b  = blockIdx.z;
    const int k0 = blockIdx.y * 32;   // Tk tile
    const int d0 = blockIdx.x * 32;   // D tile
    const int tx = threadIdx.x;       // 0..31
    const int ty = threadIdx.y;       // 0..7
    const float* src = K + (size_t)b * 2048 * 1024;
    f16* khb = Kh + (size_t)b * 2048 * 1024;
    f16* ktb = Kt + (size_t)b * 1024 * 2048;
    #pragma unroll
    for (int i = ty; i < 32; i += 8) {
        f16 v = (f16)src[(size_t)(k0 + i) * 1024 + d0 + tx];
        tile[i][tx] = v;
        khb[(size_t)(k0 + i) * 1024 + d0 + tx] = v;   // coalesced in d
    }
    __syncthreads();
    #pragma unroll
    for (int i = ty; i < 32; i += 8) {
        ktb[(size_t)(d0 + i) * 2048 + k0 + tx] = tile[tx][i];  // coalesced in k
    }
}

// ---- m97-style bt-GEMM: C[M,N] = A[M,K_] * B[N,K_]^T, fp16 MFMA, fp32 out ----
// grid: dim3(8, nMtiles*nNtiles); blockIdx.x = batch (XCD), y = m*nN + n.
__global__ __launch_bounds__(256) void gemm_bt(const f16* __restrict__ Amat,
                                               const f16* __restrict__ Bmat,
                                               float* __restrict__ C,
                                               int K_, int N, int nN,
                                               long sA, long sB, long sC) {
    __shared__ f16 As[BM * BK];   // 8 KB
    __shared__ f16 Bs[BN * BK];   // 8 KB
    const int tid  = threadIdx.x;
    const int lane = tid & 63;
    const int wave = tid >> 6;
    const int wm = (wave & 1) * 64;
    const int wn = (wave >> 1) * 64;
    const int bz = blockIdx.x;                    // batch -> XCD
    const int tileM = (blockIdx.y / nN) * BM;
    const int tileN = (blockIdx.y % nN) * BN;
    const f16* Ab = Amat + (size_t)bz * sA;
    const f16* Bb = Bmat + (size_t)bz * sB;
    float* Cb = C + (size_t)bz * sC;

    floatx4 zero = {0.f, 0.f, 0.f, 0.f};
    floatx4 acc[4][4];
    #pragma unroll
    for (int i = 0; i < 4; i++)
        #pragma unroll
        for (int j = 0; j < 4; j++) acc[i][j] = zero;

    for (int k0 = 0; k0 < K_; k0 += BK) {
        #pragma unroll
        for (int r = 0; r < 2; r++) {
            int h = (r * 256 + tid) * 8;
            int row = h >> 5, col = h & 31;
            gl2lds16(Ab + (size_t)(tileM + row) * K_ + k0 + col, &As[h]);
        }
        #pragma unroll
        for (int r = 0; r < 2; r++) {
            int h = (r * 256 + tid) * 8;
            int row = h >> 5, col = h & 31;
            gl2lds16(Bb + (size_t)(tileN + row) * K_ + k0 + col, &Bs[h]);
        }
        __syncthreads();

        const int mr = lane & 15;
        const int kq = (lane >> 4) * 8;
        half8 af[4], bf[4];
        #pragma unroll
        for (int i = 0; i < 4; i++)
            af[i] = *(const half8*)&As[(wm + i * 16 + mr) * BK + kq];
        #pragma unroll
        for (int j = 0; j < 4; j++)
            bf[j] = *(const half8*)&Bs[(wn + j * 16 + mr) * BK + kq];
        #pragma unroll
        for (int i = 0; i < 4; i++)
            #pragma unroll
            for (int j = 0; j < 4; j++)
                acc[i][j] = __builtin_amdgcn_mfma_f32_16x16x32_f16(af[i], bf[j], acc[i][j], 0, 0, 0);
        __syncthreads();
    }

    // epilogue: C/D layout col=lane&15, row=(lane>>4)*4+reg
    const int r0 = (lane >> 4) * 4;
    const int cn = lane & 15;
    #pragma unroll
    for (int i = 0; i < 4; i++) {
        #pragma unroll
        for (int j = 0; j < 4; j++) {
            int col = tileN + wn + j * 16 + cn;
            #pragma unroll
            for (int r = 0; r < 4; r++) {
                int row = tileM + wm + i * 16 + r0 + r;
                Cb[(size_t)row * N + col] = acc[i][j][r];
            }
        }
    }
}

// ---- row softmax: fp32 in-place + fp16 copy to ws ----
__global__ __launch_bounds__(256) void softmax_rows(float* __restrict__ S,
                                                    f16* __restrict__ Wh) {
    const size_t row = blockIdx.x;
    float* p = S + row * 2048;
    f16* ph = Wh + row * 2048;
    const int tid = threadIdx.x;
    const int lane = tid & 63;
    const int wave = tid >> 6;
    __shared__ float red[8];

    float4 va = ((const float4*)p)[tid];
    float4 vb = ((const float4*)p)[tid + 256];
    float m = fmaxf(fmaxf(fmaxf(va.x, va.y), fmaxf(va.z, va.w)),
                    fmaxf(fmaxf(vb.x, vb.y), fmaxf(vb.z, vb.w)));
    #pragma unroll
    for (int off = 32; off; off >>= 1) m = fmaxf(m, __shfl_xor(m, off));
    if (lane == 0) red[wave] = m;
    __syncthreads();
    m = fmaxf(fmaxf(red[0], red[1]), fmaxf(red[2], red[3]));

    va.x = __expf(va.x - m); va.y = __expf(va.y - m);
    va.z = __expf(va.z - m); va.w = __expf(va.w - m);
    vb.x = __expf(vb.x - m); vb.y = __expf(vb.y - m);
    vb.z = __expf(vb.z - m); vb.w = __expf(vb.w - m);
    float s = va.x + va.y + va.z + va.w + vb.x + vb.y + vb.z + vb.w;
    #pragma unroll
    for (int off = 32; off; off >>= 1) s += __shfl_xor(s, off);
    if (lane == 0) red[4 + wave] = s;
    __syncthreads();
    s = red[4] + red[5] + red[6] + red[7];
    float inv = 1.0f / s;
    va.x *= inv; va.y *= inv; va.z *= inv; va.w *= inv;
    vb.x *= inv; vb.y *= inv; vb.z *= inv; vb.w *= inv;
    ((float4*)p)[tid] = va;
    ((float4*)p)[tid + 256] = vb;
    half4 ha, hb;
    ha[0] = (f16)va.x; ha[1] = (f16)va.y; ha[2] = (f16)va.z; ha[3] = (f16)va.w;
    hb[0] = (f16)vb.x; hb[1] = (f16)vb.y; hb[2] = (f16)vb.z; hb[3] = (f16)vb.w;
    ((half4*)ph)[tid] = ha;
    ((half4*)ph)[tid + 256] = hb;
}

extern "C" void kernel_launch(void* const* d_in, const int* in_sizes, int n_in,
                              void* d_out, int out_size, void* d_ws, size_t ws_size,
                              hipStream_t stream) {
    const float* Q = (const float*)d_in[0];   // [8,2048,1024]
    const float* K = (const float*)d_in[1];   // [8,2048,1024]
    float* ctx = (float*)d_out;               // [8,2048,1024]
    float* W   = (float*)d_out + 16777216;    // [8,2048,2048]

    f16* Qh = (f16*)d_ws;        // 32 MB
    f16* Kh = Qh + 16777216;     // 32 MB
    f16* Kt = Kh + 16777216;     // 32 MB, [B][D][Tk]
    f16* Wh = (f16*)d_ws;        // 64 MB, aliases Qh+Kh (dead after QK GEMM)

    // 1. converts
    cvt_f32_f16<<<16384, 256, 0, stream>>>(Q, Qh, 4194304);
    k_cvt_transpose<<<dim3(32, 64, 8), dim3(32, 8), 0, stream>>>(K, Kh, Kt);

    // 2. scores = Qh @ Kh^T  (M=2048, N=2048, K_=1024) -> W region (raw)
    gemm_bt<<<dim3(8, 256), 256, 0, stream>>>(
        Qh, Kh, W, 1024, 2048, 16, 2048L * 1024, 2048L * 1024, 2048L * 2048);

    // 3. softmax rows (16384 rows of 2048): fp32 in place + fp16 -> Wh
    softmax_rows<<<16384, 256, 0, stream>>>(W, Wh);

    // 4. context = Wh @ Kt^T  (M=2048, N=1024, K_=2048)
    gemm_bt<<<dim3(8, 128), 256, 0, stream>>>(
        Wh, Kt, ctx, 2048, 1024, 8, 2048L * 2048, 1024L * 2048, 2048L * 1024);
}

// Round 3
// 524.245 us; speedup vs baseline: 1.1381x; 1.0760x over previous
//
#include <hip/hip_runtime.h>

// Problem: B=8, Tq=2048, Tk=2048, D=1024 (all fp32 in/out)
//   scores  = Q @ K^T            [B,Tq,Tk]
//   weights = softmax(scores)    (output 1, at d_out + 16777216)
//   context = weights @ K        (output 0, at d_out)
//
// ws layout (96 MB):
//   phase 1:  Qh f16 [B][Tq][D] @ 0       (32 MB)
//             Kh f16 [B][Tk][D] @ 32 MB   (32 MB)
//             Kt f16 [B][D][Tk] @ 64 MB   (32 MB)
//   phase 2 (after QK GEMM, Qh/Kh dead):
//             Wh f16 [B][Tq][Tk] @ 0      (64 MB)   <- written by softmax
//
// GEMM: BK=64, XOR-swizzled LDS (global_load_lds forces lane-ordered LDS
// dest, so the swizzle is applied to the *global source* chunk index).
// XCD trick: grid dim3(8, tiles) -> flat%8 == blockIdx.x == batch.

typedef _Float16 f16;
typedef _Float16 half4 __attribute__((ext_vector_type(4)));
typedef _Float16 half8 __attribute__((ext_vector_type(8)));
typedef float floatx4 __attribute__((ext_vector_type(4)));

#define BM 128
#define BN 128
#define BK 64

__device__ __forceinline__ void gl2lds16(const void* g, void* l) {
    __builtin_amdgcn_global_load_lds(
        (const __attribute__((address_space(1))) unsigned int*)g,
        (__attribute__((address_space(3))) unsigned int*)l,
        16, 0, 0);
}

// ---- fp32 -> fp16 convert ----
__global__ __launch_bounds__(256) void cvt_f32_f16(const float* __restrict__ src,
                                                   f16* __restrict__ dst, int n4) {
    int i = blockIdx.x * 256 + threadIdx.x;
    if (i >= n4) return;
    float4 v = ((const float4*)src)[i];
    half4 h;
    h[0] = (f16)v.x; h[1] = (f16)v.y; h[2] = (f16)v.z; h[3] = (f16)v.w;
    ((half4*)dst)[i] = h;
}

// ---- K: fp32 -> fp16 row-major copy + transposed copy (64x64 tiles) ----
__global__ __launch_bounds__(256) void k_cvt_transpose(const float* __restrict__ K,
                                                       f16* __restrict__ Kh,
                                                       f16* __restrict__ Kt) {
    __shared__ f16 tile[64][72];                  // +8 f16 pad
    const int b  = blockIdx.z;
    const int k0 = blockIdx.y * 64;               // Tk tile
    const int d0 = blockIdx.x * 64;               // D tile
    const float* src = K + (size_t)b * 2048 * 1024;
    f16* khb = Kh + (size_t)b * 2048 * 1024;
    f16* ktb = Kt + (size_t)b * 1024 * 2048;
    const int r  = threadIdx.x >> 4;              // 0..15
    const int c4 = (threadIdx.x & 15) * 4;        // 0..60
    #pragma unroll
    for (int it = 0; it < 4; it++) {
        int kr = it * 16 + r;
        float4 v = *(const float4*)&src[(size_t)(k0 + kr) * 1024 + d0 + c4];
        half4 h;
        h[0] = (f16)v.x; h[1] = (f16)v.y; h[2] = (f16)v.z; h[3] = (f16)v.w;
        *(half4*)&khb[(size_t)(k0 + kr) * 1024 + d0 + c4] = h;
        *(half4*)&tile[kr][c4] = h;
    }
    __syncthreads();
    #pragma unroll
    for (int it = 0; it < 4; it++) {
        int dr = it * 16 + r;
        half4 h;
        h[0] = tile[c4 + 0][dr]; h[1] = tile[c4 + 1][dr];
        h[2] = tile[c4 + 2][dr]; h[3] = tile[c4 + 3][dr];
        *(half4*)&ktb[(size_t)(d0 + dr) * 2048 + k0 + c4] = h;
    }
}

// ---- bt-GEMM: C[M,N] = A[M,K_] * B[N,K_]^T, fp16 MFMA, fp32 out ----
// BK=64, XOR-swizzled LDS chunks. grid dim3(8, nM*nN), x = batch.
__global__ __launch_bounds__(256) void gemm_bt(const f16* __restrict__ Amat,
                                               const f16* __restrict__ Bmat,
                                               float* __restrict__ C,
                                               int K_, int N, int nN,
                                               long sA, long sB, long sC) {
    __shared__ f16 As[BM * BK];   // 16 KB
    __shared__ f16 Bs[BN * BK];   // 16 KB
    const int tid  = threadIdx.x;
    const int lane = tid & 63;
    const int wave = tid >> 6;
    const int wm = (wave & 1) * 64;
    const int wn = (wave >> 1) * 64;
    const int bz = blockIdx.x;                    // batch -> XCD
    const int tileM = (blockIdx.y / nN) * BM;
    const int tileN = (blockIdx.y % nN) * BN;
    const f16* Ab = Amat + (size_t)bz * sA;
    const f16* Bb = Bmat + (size_t)bz * sB;
    float* Cb = C + (size_t)bz * sC;

    floatx4 zero = {0.f, 0.f, 0.f, 0.f};
    floatx4 acc[4][4];
    #pragma unroll
    for (int i = 0; i < 4; i++)
        #pragma unroll
        for (int j = 0; j < 4; j++) acc[i][j] = zero;

    const int mr = lane & 15;
    const int q  = lane >> 4;        // 0..3
    const int sw = mr & 7;           // read-side XOR key (row&7 == mr&7)

    for (int k0 = 0; k0 < K_; k0 += BK) {
        // stage A: 1024 chunks of 16B, 4 per thread; store global chunk
        // (cc ^ (row&7)) at LDS chunk cc  (lane-ordered LDS dest).
        #pragma unroll
        for (int r = 0; r < 4; r++) {
            int h = r * 256 + tid;               // chunk index
            int row = h >> 3, cc = h & 7;
            int gcc = cc ^ (row & 7);
            gl2lds16(Ab + (size_t)(tileM + row) * K_ + k0 + gcc * 8, &As[h * 8]);
        }
        #pragma unroll
        for (int r = 0; r < 4; r++) {
            int h = r * 256 + tid;
            int row = h >> 3, cc = h & 7;
            int gcc = cc ^ (row & 7);
            gl2lds16(Bb + (size_t)(tileN + row) * K_ + k0 + gcc * 8, &Bs[h * 8]);
        }
        __syncthreads();

        #pragma unroll
        for (int s = 0; s < 2; s++) {
            const int lc = ((s << 2) | q) ^ sw;  // physical chunk for this frag
            half8 af[4], bf[4];
            #pragma unroll
            for (int i = 0; i < 4; i++)
                af[i] = *(const half8*)&As[(wm + i * 16 + mr) * BK + lc * 8];
            #pragma unroll
            for (int j = 0; j < 4; j++)
                bf[j] = *(const half8*)&Bs[(wn + j * 16 + mr) * BK + lc * 8];
            #pragma unroll
            for (int i = 0; i < 4; i++)
                #pragma unroll
                for (int j = 0; j < 4; j++)
                    acc[i][j] = __builtin_amdgcn_mfma_f32_16x16x32_f16(af[i], bf[j], acc[i][j], 0, 0, 0);
        }
        __syncthreads();
    }

    // epilogue: C/D layout col=lane&15, row=(lane>>4)*4+reg
    const int r0 = q * 4;
    const int cn = mr;
    #pragma unroll
    for (int i = 0; i < 4; i++) {
        #pragma unroll
        for (int j = 0; j < 4; j++) {
            int col = tileN + wn + j * 16 + cn;
            #pragma unroll
            for (int r = 0; r < 4; r++) {
                int row = tileM + wm + i * 16 + r0 + r;
                Cb[(size_t)row * N + col] = acc[i][j][r];
            }
        }
    }
}

// ---- row softmax: fp32 in-place + fp16 copy to ws ----
__global__ __launch_bounds__(256) void softmax_rows(float* __restrict__ S,
                                                    f16* __restrict__ Wh) {
    const size_t row = blockIdx.x;
    float* p = S + row * 2048;
    f16* ph = Wh + row * 2048;
    const int tid = threadIdx.x;
    const int lane = tid & 63;
    const int wave = tid >> 6;
    __shared__ float red[8];

    float4 va = ((const float4*)p)[tid];
    float4 vb = ((const float4*)p)[tid + 256];
    float m = fmaxf(fmaxf(fmaxf(va.x, va.y), fmaxf(va.z, va.w)),
                    fmaxf(fmaxf(vb.x, vb.y), fmaxf(vb.z, vb.w)));
    #pragma unroll
    for (int off = 32; off; off >>= 1) m = fmaxf(m, __shfl_xor(m, off));
    if (lane == 0) red[wave] = m;
    __syncthreads();
    m = fmaxf(fmaxf(red[0], red[1]), fmaxf(red[2], red[3]));

    va.x = __expf(va.x - m); va.y = __expf(va.y - m);
    va.z = __expf(va.z - m); va.w = __expf(va.w - m);
    vb.x = __expf(vb.x - m); vb.y = __expf(vb.y - m);
    vb.z = __expf(vb.z - m); vb.w = __expf(vb.w - m);
    float s = va.x + va.y + va.z + va.w + vb.x + vb.y + vb.z + vb.w;
    #pragma unroll
    for (int off = 32; off; off >>= 1) s += __shfl_xor(s, off);
    if (lane == 0) red[4 + wave] = s;
    __syncthreads();
    s = red[4] + red[5] + red[6] + red[7];
    float inv = 1.0f / s;
    va.x *= inv; va.y *= inv; va.z *= inv; va.w *= inv;
    vb.x *= inv; vb.y *= inv; vb.z *= inv; vb.w *= inv;
    ((float4*)p)[tid] = va;
    ((float4*)p)[tid + 256] = vb;
    half4 ha, hb;
    ha[0] = (f16)va.x; ha[1] = (f16)va.y; ha[2] = (f16)va.z; ha[3] = (f16)va.w;
    hb[0] = (f16)vb.x; hb[1] = (f16)vb.y; hb[2] = (f16)vb.z; hb[3] = (f16)vb.w;
    ((half4*)ph)[tid] = ha;
    ((half4*)ph)[tid + 256] = hb;
}

extern "C" void kernel_launch(void* const* d_in, const int* in_sizes, int n_in,
                              void* d_out, int out_size, void* d_ws, size_t ws_size,
                              hipStream_t stream) {
    const float* Q = (const float*)d_in[0];   // [8,2048,1024]
    const float* K = (const float*)d_in[1];   // [8,2048,1024]
    float* ctx = (float*)d_out;               // [8,2048,1024]
    float* W   = (float*)d_out + 16777216;    // [8,2048,2048]

    f16* Qh = (f16*)d_ws;        // 32 MB
    f16* Kh = Qh + 16777216;     // 32 MB
    f16* Kt = Kh + 16777216;     // 32 MB, [B][D][Tk]
    f16* Wh = (f16*)d_ws;        // 64 MB, aliases Qh+Kh (dead after QK GEMM)

    // 1. converts
    cvt_f32_f16<<<16384, 256, 0, stream>>>(Q, Qh, 4194304);
    k_cvt_transpose<<<dim3(16, 32, 8), 256, 0, stream>>>(K, Kh, Kt);

    // 2. scores = Qh @ Kh^T  (M=2048, N=2048, K_=1024) -> W region (raw)
    gemm_bt<<<dim3(8, 256), 256, 0, stream>>>(
        Qh, Kh, W, 1024, 2048, 16, 2048L * 1024, 2048L * 1024, 2048L * 2048);

    // 3. softmax rows (16384 rows of 2048): fp32 in place + fp16 -> Wh
    softmax_rows<<<16384, 256, 0, stream>>>(W, Wh);

    // 4. context = Wh @ Kt^T  (M=2048, N=1024, K_=2048)
    gemm_bt<<<dim3(8, 128), 256, 0, stream>>>(
        Wh, Kt, ctx, 2048, 1024, 8, 2048L * 2048, 1024L * 2048, 2048L * 1024);
}

// Round 4
// 491.896 us; speedup vs baseline: 1.2130x; 1.0658x over previous
//
#include <hip/hip_runtime.h>

// Problem: B=8, Tq=2048, Tk=2048, D=1024 (all fp32 in/out)
//   scores  = Q @ K^T            [B,Tq,Tk]
//   weights = softmax(scores)    (output 1, at d_out + 16777216)
//   context = weights @ K        (output 0, at d_out)
//
// ws layout (96 MB):
//   phase 1:  Qh f16 [B][Tq][D] @ 0       (32 MB)
//             Kh f16 [B][Tk][D] @ 32 MB   (32 MB)
//             Kt f16 [B][D][Tk] @ 64 MB   (32 MB)
//   phase 2 (after QK GEMM, Qh/Kh dead):
//             Wh f16 [B][Tq][Tk] @ 0      (64 MB)   <- written by softmax
//
// GEMM: 32x32x16 MFMA (half the issues of 16x16x32 for same FLOP; µbench
// 2495 vs 2075 TF), BK=64, XOR-swizzled LDS (swizzle applied to the
// *global source* chunk since global_load_lds pins LDS dest to lane order).
// XCD trick: grid dim3(8, tiles) -> flat%8 == blockIdx.x == batch.

typedef _Float16 f16;
typedef _Float16 half4 __attribute__((ext_vector_type(4)));
typedef _Float16 half8 __attribute__((ext_vector_type(8)));
typedef float floatx16 __attribute__((ext_vector_type(16)));

#define BM 128
#define BN 128
#define BK 64

__device__ __forceinline__ void gl2lds16(const void* g, void* l) {
    __builtin_amdgcn_global_load_lds(
        (const __attribute__((address_space(1))) unsigned int*)g,
        (__attribute__((address_space(3))) unsigned int*)l,
        16, 0, 0);
}

// ---- fp32 -> fp16 convert ----
__global__ __launch_bounds__(256) void cvt_f32_f16(const float* __restrict__ src,
                                                   f16* __restrict__ dst, int n4) {
    int i = blockIdx.x * 256 + threadIdx.x;
    if (i >= n4) return;
    float4 v = ((const float4*)src)[i];
    half4 h;
    h[0] = (f16)v.x; h[1] = (f16)v.y; h[2] = (f16)v.z; h[3] = (f16)v.w;
    ((half4*)dst)[i] = h;
}

// ---- K: fp32 -> fp16 row-major copy + transposed copy (64x64 tiles) ----
__global__ __launch_bounds__(256) void k_cvt_transpose(const float* __restrict__ K,
                                                       f16* __restrict__ Kh,
                                                       f16* __restrict__ Kt) {
    __shared__ f16 tile[64][72];                  // +8 f16 pad
    const int b  = blockIdx.z;
    const int k0 = blockIdx.y * 64;               // Tk tile
    const int d0 = blockIdx.x * 64;               // D tile
    const float* src = K + (size_t)b * 2048 * 1024;
    f16* khb = Kh + (size_t)b * 2048 * 1024;
    f16* ktb = Kt + (size_t)b * 1024 * 2048;
    const int r  = threadIdx.x >> 4;              // 0..15
    const int c4 = (threadIdx.x & 15) * 4;        // 0..60
    #pragma unroll
    for (int it = 0; it < 4; it++) {
        int kr = it * 16 + r;
        float4 v = *(const float4*)&src[(size_t)(k0 + kr) * 1024 + d0 + c4];
        half4 h;
        h[0] = (f16)v.x; h[1] = (f16)v.y; h[2] = (f16)v.z; h[3] = (f16)v.w;
        *(half4*)&khb[(size_t)(k0 + kr) * 1024 + d0 + c4] = h;
        *(half4*)&tile[kr][c4] = h;
    }
    __syncthreads();
    #pragma unroll
    for (int it = 0; it < 4; it++) {
        int dr = it * 16 + r;
        half4 h;
        h[0] = tile[c4 + 0][dr]; h[1] = tile[c4 + 1][dr];
        h[2] = tile[c4 + 2][dr]; h[3] = tile[c4 + 3][dr];
        *(half4*)&ktb[(size_t)(d0 + dr) * 2048 + k0 + c4] = h;
    }
}

// ---- bt-GEMM: C[M,N] = A[M,K_] * B[N,K_]^T, 32x32x16 f16 MFMA, fp32 out ----
// BK=64, XOR-swizzled LDS chunks. grid dim3(8, nM*nN), x = batch.
__global__ __launch_bounds__(256) void gemm_bt(const f16* __restrict__ Amat,
                                               const f16* __restrict__ Bmat,
                                               float* __restrict__ C,
                                               int K_, int N, int nN,
                                               long sA, long sB, long sC) {
    __shared__ f16 As[BM * BK];   // 16 KB
    __shared__ f16 Bs[BN * BK];   // 16 KB
    const int tid  = threadIdx.x;
    const int lane = tid & 63;
    const int wave = tid >> 6;
    const int wm = (wave & 1) * 64;
    const int wn = (wave >> 1) * 64;
    const int bz = blockIdx.x;                    // batch -> XCD
    const int tileM = (blockIdx.y / nN) * BM;
    const int tileN = (blockIdx.y % nN) * BN;
    const f16* Ab = Amat + (size_t)bz * sA;
    const f16* Bb = Bmat + (size_t)bz * sB;
    float* Cb = C + (size_t)bz * sC;

    floatx16 acc[2][2];
    #pragma unroll
    for (int t = 0; t < 2; t++)
        #pragma unroll
        for (int u = 0; u < 2; u++)
            #pragma unroll
            for (int r = 0; r < 16; r++) acc[t][u][r] = 0.f;

    const int l31 = lane & 31;       // row within a 32-tile (A/B operand)
    const int khalf = lane >> 5;     // k-half selector
    const int sw = lane & 7;         // read-side XOR key (row&7 == lane&7)

    for (int k0 = 0; k0 < K_; k0 += BK) {
        // stage: 1024 chunks of 16B per matrix, 4 per thread; global chunk
        // (cc ^ (row&7)) lands at LDS chunk cc (lane-ordered LDS dest).
        #pragma unroll
        for (int r = 0; r < 4; r++) {
            int h = r * 256 + tid;               // chunk index
            int row = h >> 3, cc = h & 7;
            int gcc = cc ^ (row & 7);
            gl2lds16(Ab + (size_t)(tileM + row) * K_ + k0 + gcc * 8, &As[h * 8]);
        }
        #pragma unroll
        for (int r = 0; r < 4; r++) {
            int h = r * 256 + tid;
            int row = h >> 3, cc = h & 7;
            int gcc = cc ^ (row & 7);
            gl2lds16(Bb + (size_t)(tileN + row) * K_ + k0 + gcc * 8, &Bs[h * 8]);
        }
        __syncthreads();

        // 4 k-steps of 16; A-frag: row=lane&31, k=(lane>>5)*8+j
        #pragma unroll
        for (int s = 0; s < 4; s++) {
            const int pc = (s * 2 + khalf) ^ sw;   // physical 16B chunk
            half8 af[2], bf[2];
            #pragma unroll
            for (int t = 0; t < 2; t++)
                af[t] = *(const half8*)&As[(wm + t * 32 + l31) * BK + pc * 8];
            #pragma unroll
            for (int u = 0; u < 2; u++)
                bf[u] = *(const half8*)&Bs[(wn + u * 32 + l31) * BK + pc * 8];
            #pragma unroll
            for (int t = 0; t < 2; t++)
                #pragma unroll
                for (int u = 0; u < 2; u++)
                    acc[t][u] = __builtin_amdgcn_mfma_f32_32x32x16_f16(af[t], bf[u], acc[t][u], 0, 0, 0);
        }
        __syncthreads();
    }

    // epilogue: C/D layout col=lane&31, row=(reg&3)+8*(reg>>2)+4*(lane>>5)
    #pragma unroll
    for (int t = 0; t < 2; t++) {
        #pragma unroll
        for (int u = 0; u < 2; u++) {
            int col = tileN + wn + u * 32 + l31;
            int rbase = tileM + wm + t * 32 + 4 * khalf;
            #pragma unroll
            for (int r = 0; r < 16; r++) {
                int row = rbase + (r & 3) + 8 * (r >> 2);
                Cb[(size_t)row * N + col] = acc[t][u][r];
            }
        }
    }
}

// ---- row softmax: fp32 in-place + fp16 copy to ws ----
__global__ __launch_bounds__(256) void softmax_rows(float* __restrict__ S,
                                                    f16* __restrict__ Wh) {
    const size_t row = blockIdx.x;
    float* p = S + row * 2048;
    f16* ph = Wh + row * 2048;
    const int tid = threadIdx.x;
    const int lane = tid & 63;
    const int wave = tid >> 6;
    __shared__ float red[8];

    float4 va = ((const float4*)p)[tid];
    float4 vb = ((const float4*)p)[tid + 256];
    float m = fmaxf(fmaxf(fmaxf(va.x, va.y), fmaxf(va.z, va.w)),
                    fmaxf(fmaxf(vb.x, vb.y), fmaxf(vb.z, vb.w)));
    #pragma unroll
    for (int off = 32; off; off >>= 1) m = fmaxf(m, __shfl_xor(m, off));
    if (lane == 0) red[wave] = m;
    __syncthreads();
    m = fmaxf(fmaxf(red[0], red[1]), fmaxf(red[2], red[3]));

    va.x = __expf(va.x - m); va.y = __expf(va.y - m);
    va.z = __expf(va.z - m); va.w = __expf(va.w - m);
    vb.x = __expf(vb.x - m); vb.y = __expf(vb.y - m);
    vb.z = __expf(vb.z - m); vb.w = __expf(vb.w - m);
    float s = va.x + va.y + va.z + va.w + vb.x + vb.y + vb.z + vb.w;
    #pragma unroll
    for (int off = 32; off; off >>= 1) s += __shfl_xor(s, off);
    if (lane == 0) red[4 + wave] = s;
    __syncthreads();
    s = red[4] + red[5] + red[6] + red[7];
    float inv = 1.0f / s;
    va.x *= inv; va.y *= inv; va.z *= inv; va.w *= inv;
    vb.x *= inv; vb.y *= inv; vb.z *= inv; vb.w *= inv;
    ((float4*)p)[tid] = va;
    ((float4*)p)[tid + 256] = vb;
    half4 ha, hb;
    ha[0] = (f16)va.x; ha[1] = (f16)va.y; ha[2] = (f16)va.z; ha[3] = (f16)va.w;
    hb[0] = (f16)vb.x; hb[1] = (f16)vb.y; hb[2] = (f16)vb.z; hb[3] = (f16)vb.w;
    ((half4*)ph)[tid] = ha;
    ((half4*)ph)[tid + 256] = hb;
}

extern "C" void kernel_launch(void* const* d_in, const int* in_sizes, int n_in,
                              void* d_out, int out_size, void* d_ws, size_t ws_size,
                              hipStream_t stream) {
    const float* Q = (const float*)d_in[0];   // [8,2048,1024]
    const float* K = (const float*)d_in[1];   // [8,2048,1024]
    float* ctx = (float*)d_out;               // [8,2048,1024]
    float* W   = (float*)d_out + 16777216;    // [8,2048,2048]

    f16* Qh = (f16*)d_ws;        // 32 MB
    f16* Kh = Qh + 16777216;     // 32 MB
    f16* Kt = Kh + 16777216;     // 32 MB, [B][D][Tk]
    f16* Wh = (f16*)d_ws;        // 64 MB, aliases Qh+Kh (dead after QK GEMM)

    // 1. converts
    cvt_f32_f16<<<16384, 256, 0, stream>>>(Q, Qh, 4194304);
    k_cvt_transpose<<<dim3(16, 32, 8), 256, 0, stream>>>(K, Kh, Kt);

    // 2. scores = Qh @ Kh^T  (M=2048, N=2048, K_=1024) -> W region (raw)
    gemm_bt<<<dim3(8, 256), 256, 0, stream>>>(
        Qh, Kh, W, 1024, 2048, 16, 2048L * 1024, 2048L * 1024, 2048L * 2048);

    // 3. softmax rows (16384 rows of 2048): fp32 in place + fp16 -> Wh
    softmax_rows<<<16384, 256, 0, stream>>>(W, Wh);

    // 4. context = Wh @ Kt^T  (M=2048, N=1024, K_=2048)
    gemm_bt<<<dim3(8, 128), 256, 0, stream>>>(
        Wh, Kt, ctx, 2048, 1024, 8, 2048L * 2048, 1024L * 2048, 2048L * 1024);
}